// Round 18
// baseline (442.141 us; speedup 1.0000x reference)
//
#include <hip/hip_runtime.h>
#include <hip/hip_bf16.h>
#include <stdint.h>

typedef __bf16  bf16x8 __attribute__((ext_vector_type(8)));
typedef __bf16  bf16x4 __attribute__((ext_vector_type(4)));
typedef float   f32x16 __attribute__((ext_vector_type(16)));
typedef uint32_t u32x4 __attribute__((ext_vector_type(4)));

#define S     2048
#define D     128
#define TKV   64            // kv rows per staged tile
#define NQB   16            // q-blocks of 128 per head
#define THR2  11.5415603f   // 8 * log2(e)
#define KROW(reg) ((((reg) & 3) + 8 * ((reg) >> 2)) + 4 * hi)

__device__ __forceinline__ uint32_t cvt_pk(float lo, float hi2) {
    uint32_t u;
    asm("v_cvt_pk_bf16_f32 %0, %1, %2" : "=v"(u) : "v"(lo), "v"(hi2));
    return u;
}
__device__ __forceinline__ float exp2fast(float x) {
    return __builtin_amdgcn_exp2f(x);
}
__device__ __forceinline__ void gl2lds16(const void* g, void* l) {
    __builtin_amdgcn_global_load_lds(
        (const __attribute__((address_space(1))) void*)g,
        (__attribute__((address_space(3))) void*)l, 16, 0, 0);
}

// ====== kernel A: pack K and V^T (bf16) into pre-swizzled 64-kv tile images ==
__global__ __launch_bounds__(256) void pack_kv(
    const float* __restrict__ K, const float* __restrict__ V,
    __bf16* __restrict__ Kp, __bf16* __restrict__ Vp)
{
    const int bh = blockIdx.x, t = blockIdx.y;      // t = 32-kv subtile
    const int tid = threadIdx.x;
    const int kv0 = t * 32;
    const int pair = t >> 1, half = t & 1;

    {   // K: convert into swizzled image half
        const float* src = K + ((size_t)bh * S + kv0) * D;
        char* dst = (char*)Kp + ((size_t)(bh * 32 + pair)) * 16384 + half * 8192;
        #pragma unroll
        for (int cc = 0; cc < 2; ++cc) {
            const int c = cc * 256 + tid;           // 0..511 16B chunks
            const int row = c >> 4, col16 = c & 15;
            const float4 a = *reinterpret_cast<const float4*>(src + row * D + col16 * 8);
            const float4 b = *reinterpret_cast<const float4*>(src + row * D + col16 * 8 + 4);
            bf16x8 o;
            o[0]=(__bf16)a.x; o[1]=(__bf16)a.y; o[2]=(__bf16)a.z; o[3]=(__bf16)a.w;
            o[4]=(__bf16)b.x; o[5]=(__bf16)b.y; o[6]=(__bf16)b.z; o[7]=(__bf16)b.w;
            *reinterpret_cast<bf16x8*>(
                dst + row * 256 + ((col16 * 16) ^ ((row & 15) << 4))) = o;
        }
    }

    __shared__ __bf16 lds[32][136];
    {   // V -> LDS
        const float* src = V + ((size_t)bh * S + kv0) * D;
        #pragma unroll
        for (int it = 0; it < 4; ++it) {
            const int id = it * 256 + tid;
            const int row = id >> 5, c4 = id & 31;
            float4 v = *reinterpret_cast<const float4*>(src + row * D + c4 * 4);
            bf16x4 b4;
            b4[0]=(__bf16)v.x; b4[1]=(__bf16)v.y; b4[2]=(__bf16)v.z; b4[3]=(__bf16)v.w;
            *reinterpret_cast<bf16x4*>(&lds[row][c4 * 4]) = b4;
        }
    }
    __syncthreads();
    {   // transpose out: Vt pair image
        char* dst = (char*)Vp + ((size_t)(bh * 32 + pair)) * 16384;
        #pragma unroll
        for (int cc = 0; cc < 2; ++cc) {
            const int c = cc * 256 + tid;           // 0..511
            const int d = c >> 2, c8 = c & 3;
            bf16x8 o;
            #pragma unroll
            for (int k = 0; k < 8; ++k) o[k] = lds[c8 * 8 + k][d];
            const int addr = d * 128 + (((half * 4 + c8) ^ (d & 7)) << 4);
            *reinterpret_cast<bf16x8*>(dst + addr) = o;
        }
    }
}

// ====== kernel B: 4 waves x 32 q-rows, 32x32 MFMA; K via gload_lds, V from L2
__global__ __launch_bounds__(256, 4) void attn_fwd(
    const float* __restrict__ Q, const __bf16* __restrict__ Kp,
    const __bf16* __restrict__ Vp, float* __restrict__ O)
{
    const int bh = blockIdx.x;
    const int y  = blockIdx.y;
    // pairing remap: co-resident blocks (y, y+8) have qt sums = 15 -> uniform
    const int qt = (y < 8) ? (15 - y) : (y - 8);
    const int tid  = threadIdx.x;
    const int w    = tid >> 6;
    const int lane = tid & 63;
    const int c    = lane & 31;
    const int hi   = lane >> 5;

    const float* Qh = Q + (size_t)bh * S * D;
    float*       Oh = O + (size_t)bh * S * D;
    const char*  Kbase = (const char*)Kp + (size_t)bh * 32 * 16384;
    const char*  Vbase = (const char*)Vp + (size_t)bh * 32 * 16384;

    const int q0w = qt * 128 + w * 32;      // wave's first q row

    __shared__ __align__(16) __bf16 K_sh[2][TKV * D];   // 16KB each (K only)

    const float scale = 0.08838834764831845f * 1.4426950408889634f;

    // ---- Q fragments (B operand): col = q0w+c, k(d) = ks*16 + hi*8 + e ----
    bf16x8 qfrag[8];
    {
        const float* qrow = Qh + (size_t)(q0w + c) * D;
        #pragma unroll
        for (int ks = 0; ks < 8; ++ks) {
            const int d0 = ks * 16 + hi * 8;
            float4 a = *reinterpret_cast<const float4*>(qrow + d0);
            float4 b = *reinterpret_cast<const float4*>(qrow + d0 + 4);
            a.x*=scale; a.y*=scale; a.z*=scale; a.w*=scale;
            b.x*=scale; b.y*=scale; b.z*=scale; b.w*=scale;
            bf16x8 f;
            f[0]=(__bf16)a.x; f[1]=(__bf16)a.y; f[2]=(__bf16)a.z; f[3]=(__bf16)a.w;
            f[4]=(__bf16)b.x; f[5]=(__bf16)b.y; f[6]=(__bf16)b.z; f[7]=(__bf16)b.w;
            qfrag[ks] = f;
        }
    }

    auto STAGE = [&](int buf, int t64) {   // K only: 4 x 16B per thread
        const char* ks = Kbase + (size_t)t64 * 16384 + w * 4096 + lane * 16;
        char* kd = (char*)(&K_sh[buf][0]) + w * 4096;   // wave-uniform base
        #pragma unroll
        for (int i = 0; i < 4; ++i)
            gl2lds16(ks + i * 1024, kd + i * 1024);
    };

    f32x16 acc_o[4];
    #pragma unroll
    for (int dt = 0; dt < 4; ++dt)
        #pragma unroll
        for (int i = 0; i < 16; ++i) acc_o[dt][i] = 0.f;
    float m_run = -1e30f, l_run = 0.f;

    const int n_iter = 2 * qt + 2;          // 64-kv tiles for this block
    const int my_max = (q0w + 31) >> 6;     // wave's last live tile

    STAGE(0, 0);
    __syncthreads();
    int cur = 0;

    for (int t = 0; t < n_iter; ++t) {
        if (t + 1 < n_iter) STAGE(cur ^ 1, t + 1);   // async across compute

        if (t <= my_max) {
            const int kv0 = t * TKV;
            char* Kb = reinterpret_cast<char*>(&K_sh[cur][0]);
            const char* Vtile = Vbase + (size_t)t * 16384;  // V direct from L2
            const bool alive1 = (kv0 + 32 <= q0w + 31);

            // ---- swapped QK^T: S^T[kv][q]; lane owns q = q0w + c ----
            f32x16 st[2];
            __builtin_amdgcn_s_setprio(1);
            #pragma unroll
            for (int sub = 0; sub < 2; ++sub) {
                #pragma unroll
                for (int i = 0; i < 16; ++i) st[sub][i] = 0.f;
                if (sub == 1 && !alive1) break;
                const int row = sub * 32 + c;
                #pragma unroll
                for (int ks = 0; ks < 8; ++ks) {
                    bf16x8 kf = *reinterpret_cast<const bf16x8*>(
                        Kb + row * 256 + (((ks*2 + hi) ^ (row & 15)) << 4));
                    st[sub] = __builtin_amdgcn_mfma_f32_32x32x16_bf16(
                        kf, qfrag[ks], st[sub], 0, 0, 0);
                }
            }
            __builtin_amdgcn_s_setprio(0);

            // ---- mask + in-register online softmax (exp2, defer-max) ----
            const int q = q0w + c;
            float pmax = -1e30f;
            #pragma unroll
            for (int sub = 0; sub < 2; ++sub) {
                if (sub == 1 && !alive1) break;
                if (kv0 + sub*32 + 31 > q0w) {
                    #pragma unroll
                    for (int reg = 0; reg < 16; ++reg)
                        if (kv0 + sub*32 + KROW(reg) > q) st[sub][reg] = -1e30f;
                }
                #pragma unroll
                for (int reg = 0; reg < 16; ++reg)
                    pmax = fmaxf(pmax, st[sub][reg]);
            }
            pmax = fmaxf(pmax, __shfl_xor(pmax, 32));

            if (__any(pmax > m_run + THR2)) {        // rare (defer-max)
                const float m_new = fmaxf(m_run, pmax);
                const float corr  = exp2fast(m_run - m_new);
                l_run *= corr; m_run = m_new;
                #pragma unroll
                for (int reg = 0; reg < 16; ++reg) {
                    const float cr = __shfl(corr, KROW(reg));
                    #pragma unroll
                    for (int dt = 0; dt < 4; ++dt) acc_o[dt][reg] *= cr;
                }
            }

            float rowsum = 0.f;
            #pragma unroll
            for (int sub = 0; sub < 2; ++sub) {
                if (sub == 1 && !alive1) break;
                #pragma unroll
                for (int reg = 0; reg < 16; ++reg) {
                    const float p = exp2fast(st[sub][reg] - m_run);
                    st[sub][reg] = p;
                    rowsum += p;
                }
            }
            rowsum += __shfl_xor(rowsum, 32);
            l_run += rowsum;

            // ---- P redistribute (cvt_pk + shfl_xor 32) + PV (V from L2) ----
            #pragma unroll
            for (int ks = 0; ks < 4; ++ks) {
                if (kv0 + ks*16 > q0w + 31) break;   // dead k-slice
                const int sub = ks >> 1, k1 = (ks & 1) * 8;
                const uint32_t pkA0 = cvt_pk(st[sub][k1+0], st[sub][k1+1]);
                const uint32_t pkA1 = cvt_pk(st[sub][k1+2], st[sub][k1+3]);
                const uint32_t pkB0 = cvt_pk(st[sub][k1+4], st[sub][k1+5]);
                const uint32_t pkB1 = cvt_pk(st[sub][k1+6], st[sub][k1+7]);
                const uint32_t rA0 = (uint32_t)__shfl_xor((int)pkA0, 32);
                const uint32_t rA1 = (uint32_t)__shfl_xor((int)pkA1, 32);
                const uint32_t rB0 = (uint32_t)__shfl_xor((int)pkB0, 32);
                const uint32_t rB1 = (uint32_t)__shfl_xor((int)pkB1, 32);
                u32x4 words;
                words[0] = hi ? rB0 : pkA0;
                words[1] = hi ? rB1 : pkA1;
                words[2] = hi ? pkB0 : rA0;
                words[3] = hi ? pkB1 : rA1;
                const bf16x8 pa = __builtin_bit_cast(bf16x8, words);
                __builtin_amdgcn_s_setprio(1);
                #pragma unroll
                for (int dt = 0; dt < 4; ++dt) {
                    const int d = dt * 32 + c;
                    bf16x8 vf = *reinterpret_cast<const bf16x8*>(
                        Vtile + d * 128 + (((ks*2 + hi) ^ (d & 7)) << 4));
                    acc_o[dt] = __builtin_amdgcn_mfma_f32_32x32x16_bf16(
                        pa, vf, acc_o[dt], 0, 0, 0);
                }
                __builtin_amdgcn_s_setprio(0);
            }
        }

        __syncthreads();    // drains gload_lds + publishes next K buffer
        cur ^= 1;
    }

    // ---- epilogue: O[q0w + KROW(reg)][dt*32 + c] = acc / l ----
    const float inv = 1.0f / l_run;
    #pragma unroll
    for (int reg = 0; reg < 16; ++reg) {
        const float iv = __shfl(inv, KROW(reg));
        float* orow = Oh + (size_t)(q0w + KROW(reg)) * D + c;
        #pragma unroll
        for (int dt = 0; dt < 4; ++dt)
            orow[dt * 32] = acc_o[dt][reg] * iv;
    }
}

extern "C" void kernel_launch(void* const* d_in, const int* in_sizes, int n_in,
                              void* d_out, int out_size, void* d_ws, size_t ws_size,
                              hipStream_t stream) {
    const float* Q = (const float*)d_in[0];
    const float* K = (const float*)d_in[1];
    const float* V = (const float*)d_in[2];
    float* O = (float*)d_out;

    __bf16* Kp = (__bf16*)d_ws;               // 16MB
    __bf16* Vp = Kp + (size_t)32 * S * D;     // 16MB

    pack_kv<<<dim3(32, 64), 256, 0, stream>>>(K, V, Kp, Vp);
    attn_fwd<<<dim3(32, NQB), 256, 0, stream>>>(Q, Kp, Vp, O);
}